// Round 1
// baseline (1059.557 us; speedup 1.0000x reference)
//
#include <hip/hip_runtime.h>
#include <hip/hip_bf16.h>

// segment_sum: out[r] += edges[e]  for all e with receivers[e]==r
// edges: [E=625000, D=128] f32, receivers: [E] i32, out: [N=50000, 128] f32.
// Memory-bound scatter-add. Each edge row = 32 float4; 32 consecutive lanes
// cooperate on one edge so receivers[e] is a wave-broadcast load.

__global__ void seg_sum_atomic(const float4* __restrict__ edges,
                               const int* __restrict__ recv,
                               float* __restrict__ out,
                               int n_edges) {
    const long long total = (long long)n_edges * 32;  // float4 chunks
    long long idx = (long long)blockIdx.x * blockDim.x + threadIdx.x;
    const long long stride = (long long)gridDim.x * blockDim.x;
    for (; idx < total; idx += stride) {
        const int e = (int)(idx >> 5);   // edge index
        const int c = (int)(idx & 31);   // float4 column within row
        const float4 v = edges[(long long)e * 32 + c];
        const int r = recv[e];
        float* o = out + (long long)r * 128 + c * 4;
        atomicAdd(o + 0, v.x);
        atomicAdd(o + 1, v.y);
        atomicAdd(o + 2, v.z);
        atomicAdd(o + 3, v.w);
    }
}

extern "C" void kernel_launch(void* const* d_in, const int* in_sizes, int n_in,
                              void* d_out, int out_size, void* d_ws, size_t ws_size,
                              hipStream_t stream) {
    const float* edges = (const float*)d_in[0];
    const int* recv = (const int*)d_in[1];
    // d_in[2] is num_nodes (scalar) — output size is out_size = 50000*128.
    float* out = (float*)d_out;

    const int n_edges = in_sizes[1];          // 625000
    // Harness poisons d_out with 0xAA; we must zero it every call.
    hipMemsetAsync(d_out, 0, (size_t)out_size * sizeof(float), stream);

    const int block = 256;
    const long long total = (long long)n_edges * 32;
    int grid = (int)((total + block - 1) / block);
    if (grid > 4096) grid = 4096;             // grid-stride the rest
    seg_sum_atomic<<<grid, block, 0, stream>>>((const float4*)edges, recv, out, n_edges);
}

// Round 2
// 265.905 us; speedup vs baseline: 3.9847x; 3.9847x over previous
//
#include <hip/hip_runtime.h>
#include <hip/hip_bf16.h>

// segment_sum: out[r] += edges[e] for receivers[e]==r.
// edges: [E=625000, D=128] f32, receivers: [E] i32, out: [N=50000, 128] f32.
//
// Round 1 showed f32-atomic scatter is TCC-atomic-throughput bound
// (80M atomics -> 1.25 GB WRITE_SIZE, 1057 us). This version does
// counting-sort by receiver, then a gather-reduce with zero feature atomics:
//   1) histogram        : counts[r]++            (int atomics, 50k counters)
//   2) exclusive scan   : offsets = scan(counts) (single 1024-thread block)
//   3) scatter ids      : eids[cursor[r]++] = e  (int atomics + 2.5MB writes)
//   4) gather-sum       : 32 lanes/node, lane c owns float4 column c;
//                         reads each 512B edge row once, one plain store/node.

#define D_F4 32  // 128 floats = 32 float4 per row

__global__ void hist_k(const int* __restrict__ recv, int* __restrict__ counts, int E) {
    int i = blockIdx.x * blockDim.x + threadIdx.x;
    const int stride = gridDim.x * blockDim.x;
    for (; i < E; i += stride)
        atomicAdd(&counts[recv[i]], 1);
}

// One block, 1024 threads: chunked exclusive scan of counts[0..N) into
// offsets[0..N], and initialize cursor = offsets[0..N).
__global__ void scan_k(const int* __restrict__ counts, int* __restrict__ offsets,
                       int* __restrict__ cursor, int N) {
    __shared__ int partials[1024];
    const int tid = threadIdx.x;
    const int chunk = (N + 1023) / 1024;
    const int lo = tid * chunk;
    const int hi = min(lo + chunk, N);

    int s = 0;
    for (int i = lo; i < hi; ++i) s += counts[i];
    partials[tid] = s;
    __syncthreads();
    // Hillis-Steele inclusive scan over the 1024 partials
    for (int d = 1; d < 1024; d <<= 1) {
        int v = (tid >= d) ? partials[tid - d] : 0;
        __syncthreads();
        partials[tid] += v;
        __syncthreads();
    }
    int run = (tid > 0) ? partials[tid - 1] : 0;
    for (int i = lo; i < hi; ++i) {
        offsets[i] = run;
        cursor[i] = run;
        run += counts[i];
    }
    if (tid == 1023) offsets[N] = partials[1023];
}

__global__ void scatter_k(const int* __restrict__ recv, int* __restrict__ cursor,
                          int* __restrict__ eids, int E) {
    int i = blockIdx.x * blockDim.x + threadIdx.x;
    const int stride = gridDim.x * blockDim.x;
    for (; i < E; i += stride) {
        const int r = recv[i];
        const int p = atomicAdd(&cursor[r], 1);
        eids[p] = i;
    }
}

__global__ void gather_k(const float4* __restrict__ edges, const int* __restrict__ eids,
                         const int* __restrict__ offsets, float4* __restrict__ out, int N) {
    const int g = (blockIdx.x * blockDim.x + threadIdx.x) >> 5;  // node index
    const int c = threadIdx.x & 31;                              // float4 column
    if (g >= N) return;
    const int lo = offsets[g];
    const int hi = offsets[g + 1];
    float4 acc = make_float4(0.f, 0.f, 0.f, 0.f);
    for (int j = lo; j < hi; ++j) {
        const int e = eids[j];  // wave-broadcast within the 32-lane group
        const float4 v = edges[(long long)e * D_F4 + c];
        acc.x += v.x; acc.y += v.y; acc.z += v.z; acc.w += v.w;
    }
    out[(long long)g * D_F4 + c] = acc;
}

// -------- fallback (round-1 atomic version) if ws_size is too small --------
__global__ void seg_sum_atomic(const float4* __restrict__ edges,
                               const int* __restrict__ recv,
                               float* __restrict__ out, int n_edges) {
    const long long total = (long long)n_edges * D_F4;
    long long idx = (long long)blockIdx.x * blockDim.x + threadIdx.x;
    const long long stride = (long long)gridDim.x * blockDim.x;
    for (; idx < total; idx += stride) {
        const int e = (int)(idx >> 5);
        const int c = (int)(idx & 31);
        const float4 v = edges[(long long)e * D_F4 + c];
        const int r = recv[e];
        float* o = out + (long long)r * 128 + c * 4;
        atomicAdd(o + 0, v.x);
        atomicAdd(o + 1, v.y);
        atomicAdd(o + 2, v.z);
        atomicAdd(o + 3, v.w);
    }
}

extern "C" void kernel_launch(void* const* d_in, const int* in_sizes, int n_in,
                              void* d_out, int out_size, void* d_ws, size_t ws_size,
                              hipStream_t stream) {
    const float* edges = (const float*)d_in[0];
    const int* recv = (const int*)d_in[1];
    float* out = (float*)d_out;

    const int E = in_sizes[1];            // 625000
    const int N = out_size / 128;         // 50000 nodes

    // workspace layout (ints): counts[N] | offsets[N+1] | cursor[N] | eids[E]
    const size_t need = (size_t)(N + (N + 1) + N + E) * sizeof(int);
    if (ws_size < need) {
        // fallback: atomic scatter
        hipMemsetAsync(d_out, 0, (size_t)out_size * sizeof(float), stream);
        const long long total = (long long)E * D_F4;
        int grid = (int)((total + 255) / 256);
        if (grid > 4096) grid = 4096;
        seg_sum_atomic<<<grid, 256, 0, stream>>>((const float4*)edges, recv, out, E);
        return;
    }

    int* counts = (int*)d_ws;
    int* offsets = counts + N;
    int* cursor = offsets + (N + 1);
    int* eids = cursor + N;

    hipMemsetAsync(counts, 0, (size_t)N * sizeof(int), stream);

    const int block = 256;
    int gridE = (E + block - 1) / block;
    if (gridE > 2048) gridE = 2048;

    hist_k<<<gridE, block, 0, stream>>>(recv, counts, E);
    scan_k<<<1, 1024, 0, stream>>>(counts, offsets, cursor, N);
    scatter_k<<<gridE, block, 0, stream>>>(recv, cursor, eids, E);

    const int gridN = (N * 32 + block - 1) / block;  // 32 lanes per node
    gather_k<<<gridN, block, 0, stream>>>((const float4*)edges, eids, offsets,
                                          (float4*)out, N);
}

// Round 3
// 249.106 us; speedup vs baseline: 4.2534x; 1.0674x over previous
//
#include <hip/hip_runtime.h>
#include <hip/hip_bf16.h>

// segment_sum: out[r] += edges[e] for receivers[e]==r.
// edges: [E=625000, D=128] f32, receivers: [E] i32, out: [N=50000, 128] f32.
//
// R1: f32-atomic scatter = TCC-atomic bound (1057 us).
// R2: counting-sort + gather (266 us) — but rocprof showed the
//     hipMemsetAsync(counts) graph node (rocclr fillBufferAligned) costs
//     ~186 us/replay with near-zero traffic. This round: custom zero kernel
//     (~2 us) instead of hipMemsetAsync; everything else unchanged.

#define D_F4 32  // 128 floats = 32 float4 per row

__global__ void zero_k(int4* __restrict__ p, int n_int4) {
    int i = blockIdx.x * blockDim.x + threadIdx.x;
    const int stride = gridDim.x * blockDim.x;
    const int4 z = make_int4(0, 0, 0, 0);
    for (; i < n_int4; i += stride) p[i] = z;
}

__global__ void hist_k(const int* __restrict__ recv, int* __restrict__ counts, int E) {
    int i = blockIdx.x * blockDim.x + threadIdx.x;
    const int stride = gridDim.x * blockDim.x;
    for (; i < E; i += stride)
        atomicAdd(&counts[recv[i]], 1);
}

// One block, 1024 threads: chunked exclusive scan of counts[0..N) into
// offsets[0..N], and initialize cursor = offsets[0..N).
__global__ void scan_k(const int* __restrict__ counts, int* __restrict__ offsets,
                       int* __restrict__ cursor, int N) {
    __shared__ int partials[1024];
    const int tid = threadIdx.x;
    const int chunk = (N + 1023) / 1024;
    const int lo = tid * chunk;
    const int hi = min(lo + chunk, N);

    int s = 0;
    for (int i = lo; i < hi; ++i) s += counts[i];
    partials[tid] = s;
    __syncthreads();
    for (int d = 1; d < 1024; d <<= 1) {
        int v = (tid >= d) ? partials[tid - d] : 0;
        __syncthreads();
        partials[tid] += v;
        __syncthreads();
    }
    int run = (tid > 0) ? partials[tid - 1] : 0;
    for (int i = lo; i < hi; ++i) {
        offsets[i] = run;
        cursor[i] = run;
        run += counts[i];
    }
    if (tid == 1023) offsets[N] = partials[1023];
}

__global__ void scatter_k(const int* __restrict__ recv, int* __restrict__ cursor,
                          int* __restrict__ eids, int E) {
    int i = blockIdx.x * blockDim.x + threadIdx.x;
    const int stride = gridDim.x * blockDim.x;
    for (; i < E; i += stride) {
        const int r = recv[i];
        const int p = atomicAdd(&cursor[r], 1);
        eids[p] = i;
    }
}

__global__ __launch_bounds__(256) void gather_k(const float4* __restrict__ edges,
                                                const int* __restrict__ eids,
                                                const int* __restrict__ offsets,
                                                float4* __restrict__ out, int N) {
    const int g = (blockIdx.x * blockDim.x + threadIdx.x) >> 5;  // node index
    const int c = threadIdx.x & 31;                              // float4 column
    if (g >= N) return;
    const int lo = offsets[g];
    const int hi = offsets[g + 1];
    float4 acc0 = make_float4(0.f, 0.f, 0.f, 0.f);
    float4 acc1 = make_float4(0.f, 0.f, 0.f, 0.f);
    int j = lo;
    // 2x unroll: two independent row loads in flight per iteration
    for (; j + 1 < hi; j += 2) {
        const int e0 = eids[j];
        const int e1 = eids[j + 1];
        const float4 v0 = edges[(long long)e0 * D_F4 + c];
        const float4 v1 = edges[(long long)e1 * D_F4 + c];
        acc0.x += v0.x; acc0.y += v0.y; acc0.z += v0.z; acc0.w += v0.w;
        acc1.x += v1.x; acc1.y += v1.y; acc1.z += v1.z; acc1.w += v1.w;
    }
    if (j < hi) {
        const int e0 = eids[j];
        const float4 v0 = edges[(long long)e0 * D_F4 + c];
        acc0.x += v0.x; acc0.y += v0.y; acc0.z += v0.z; acc0.w += v0.w;
    }
    acc0.x += acc1.x; acc0.y += acc1.y; acc0.z += acc1.z; acc0.w += acc1.w;
    out[(long long)g * D_F4 + c] = acc0;
}

// -------- fallback (atomic version) if ws_size is too small --------
__global__ void seg_sum_atomic(const float4* __restrict__ edges,
                               const int* __restrict__ recv,
                               float* __restrict__ out, int n_edges) {
    const long long total = (long long)n_edges * D_F4;
    long long idx = (long long)blockIdx.x * blockDim.x + threadIdx.x;
    const long long stride = (long long)gridDim.x * blockDim.x;
    for (; idx < total; idx += stride) {
        const int e = (int)(idx >> 5);
        const int c = (int)(idx & 31);
        const float4 v = edges[(long long)e * D_F4 + c];
        const int r = recv[e];
        float* o = out + (long long)r * 128 + c * 4;
        atomicAdd(o + 0, v.x);
        atomicAdd(o + 1, v.y);
        atomicAdd(o + 2, v.z);
        atomicAdd(o + 3, v.w);
    }
}

extern "C" void kernel_launch(void* const* d_in, const int* in_sizes, int n_in,
                              void* d_out, int out_size, void* d_ws, size_t ws_size,
                              hipStream_t stream) {
    const float* edges = (const float*)d_in[0];
    const int* recv = (const int*)d_in[1];
    float* out = (float*)d_out;

    const int E = in_sizes[1];            // 625000
    const int N = out_size / 128;         // 50000 nodes

    // workspace layout (ints): counts[N] | offsets[N+1] | cursor[N] | eids[E]
    // counts is rounded up to a multiple of 4 ints for int4 zeroing.
    const int countsPad = (N + 3) & ~3;
    const size_t need = (size_t)(countsPad + (N + 1) + N + E) * sizeof(int);
    if (ws_size < need) {
        // fallback: zero output with our own kernel, then atomic scatter
        const int nInt4 = out_size / 4;  // out_size floats -> int4 chunks
        zero_k<<<256, 256, 0, stream>>>((int4*)d_out, nInt4);
        const long long total = (long long)E * D_F4;
        int grid = (int)((total + 255) / 256);
        if (grid > 4096) grid = 4096;
        seg_sum_atomic<<<grid, 256, 0, stream>>>((const float4*)edges, recv, out, E);
        return;
    }

    int* counts = (int*)d_ws;
    int* offsets = counts + countsPad;
    int* cursor = offsets + (N + 1);
    int* eids = cursor + N;

    const int block = 256;

    // zero counts (custom kernel; hipMemsetAsync's fill was ~186 us/replay)
    zero_k<<<64, block, 0, stream>>>((int4*)counts, countsPad / 4);

    int gridE = (E + block - 1) / block;
    if (gridE > 2048) gridE = 2048;

    hist_k<<<gridE, block, 0, stream>>>(recv, counts, E);
    scan_k<<<1, 1024, 0, stream>>>(counts, offsets, cursor, N);
    scatter_k<<<gridE, block, 0, stream>>>(recv, cursor, eids, E);

    const int gridN = (N * 32 + block - 1) / block;  // 32 lanes per node
    gather_k<<<gridN, block, 0, stream>>>((const float4*)edges, eids, offsets,
                                          (float4*)out, N);
}

// Round 4
// 165.055 us; speedup vs baseline: 6.4194x; 1.5092x over previous
//
#include <hip/hip_runtime.h>
#include <hip/hip_bf16.h>

// segment_sum: out[r] += edges[e] for receivers[e]==r.
// edges: [E=625000, D=128] f32, receivers: [E] i32, out: [N=50000, 128] f32.
//
// R1: f32-atomic scatter = TCC-atomic bound (1057 us, 1.25 GB atomic RMW).
// R2: counting-sort + gather-reduce (266 us).
// R3: custom zero kernel (249 us). Learned: ~186us fillBufferAligned rows are
//     the HARNESS poisoning a ~1.3GB workspace OUTSIDE the timed graph.
// R4 (this): vectorize the latency-bound bits —
//     - scan_k: int4 loads/stores (4x fewer serial iterations on 1 CU)
//     - hist/scatter: int4 receiver loads
//     - gather: coalesced 32-eid block load + __shfl broadcast (kills the
//       serial uniform-load -> row-load dependent chain), nontemporal
//       loads/stores (all data is touch-once; nt store skips RFO).

#define D_F4 32  // 128 floats = 32 float4 per row

typedef float f32x4 __attribute__((ext_vector_type(4)));

__global__ void zero_k(int4* __restrict__ p, int n_int4) {
    int i = blockIdx.x * blockDim.x + threadIdx.x;
    const int stride = gridDim.x * blockDim.x;
    const int4 z = make_int4(0, 0, 0, 0);
    for (; i < n_int4; i += stride) p[i] = z;
}

__global__ void hist_k(const int* __restrict__ recv, int* __restrict__ counts, int E) {
    const int E4 = E >> 2;
    const int i = blockIdx.x * blockDim.x + threadIdx.x;
    const int stride = gridDim.x * blockDim.x;
    for (int k = i; k < E4; k += stride) {
        const int4 r = ((const int4*)recv)[k];
        atomicAdd(&counts[r.x], 1);
        atomicAdd(&counts[r.y], 1);
        atomicAdd(&counts[r.z], 1);
        atomicAdd(&counts[r.w], 1);
    }
    if (i < (E & 3)) atomicAdd(&counts[recv[(E4 << 2) + i]], 1);
}

// One block, 1024 threads: vectorized chunked exclusive scan of counts[0..N)
// into offsets[0..N]; cursor = copy of offsets[0..N).
__global__ void scan_k(const int* __restrict__ counts, int* __restrict__ offsets,
                       int* __restrict__ cursor, int N) {
    __shared__ int partials[1024];
    const int tid = threadIdx.x;
    int chunk = (N + 1023) >> 10;
    chunk = (chunk + 3) & ~3;                 // keep int4 alignment
    const int lo = min(tid * chunk, N);
    const int hi = min(lo + chunk, N);

    int s = 0;
    int i = lo;
    for (; i + 4 <= hi; i += 4) {
        const int4 c4 = *(const int4*)(counts + i);
        s += c4.x + c4.y + c4.z + c4.w;
    }
    for (; i < hi; ++i) s += counts[i];
    partials[tid] = s;
    __syncthreads();
    for (int d = 1; d < 1024; d <<= 1) {
        const int v = (tid >= d) ? partials[tid - d] : 0;
        __syncthreads();
        partials[tid] += v;
        __syncthreads();
    }
    int run = (tid > 0) ? partials[tid - 1] : 0;
    i = lo;
    for (; i + 4 <= hi; i += 4) {
        const int4 c4 = *(const int4*)(counts + i);
        int4 o;
        o.x = run;
        o.y = run + c4.x;
        o.z = o.y + c4.y;
        o.w = o.z + c4.z;
        run = o.w + c4.w;
        *(int4*)(offsets + i) = o;
        *(int4*)(cursor + i) = o;
    }
    for (; i < hi; ++i) { offsets[i] = run; cursor[i] = run; run += counts[i]; }
    if (tid == 1023) offsets[N] = partials[1023];
}

__global__ void scatter_k(const int* __restrict__ recv, int* __restrict__ cursor,
                          int* __restrict__ eids, int E) {
    const int E4 = E >> 2;
    const int i = blockIdx.x * blockDim.x + threadIdx.x;
    const int stride = gridDim.x * blockDim.x;
    for (int k = i; k < E4; k += stride) {
        const int4 r = ((const int4*)recv)[k];
        const int e = k << 2;
        eids[atomicAdd(&cursor[r.x], 1)] = e;
        eids[atomicAdd(&cursor[r.y], 1)] = e + 1;
        eids[atomicAdd(&cursor[r.z], 1)] = e + 2;
        eids[atomicAdd(&cursor[r.w], 1)] = e + 3;
    }
    if (i < (E & 3)) {
        const int e = (E4 << 2) + i;
        eids[atomicAdd(&cursor[recv[e]], 1)] = e;
    }
}

// 32 lanes per node; lane c owns float4 column c. Eids are loaded 32-at-a-time
// coalesced, then broadcast by register shuffle so the edge-row loads issue
// back-to-back instead of behind a serial uniform eid load.
__global__ __launch_bounds__(256) void gather_k(const float* __restrict__ edges,
                                                const int* __restrict__ eids,
                                                const int* __restrict__ offsets,
                                                float* __restrict__ out, int N) {
    const int g = (blockIdx.x * blockDim.x + threadIdx.x) >> 5;  // node
    const int c = threadIdx.x & 31;                              // float4 col
    if (g >= N) return;
    const int lo = offsets[g];
    const int hi = offsets[g + 1];

    f32x4 a0 = {0.f, 0.f, 0.f, 0.f};
    f32x4 a1 = {0.f, 0.f, 0.f, 0.f};
    const f32x4* __restrict__ erows = (const f32x4*)edges;

    for (int base = lo; base < hi; base += 32) {
        const int cnt = min(32, hi - base);
        // one coalesced load of up to 32 edge ids for this node
        const int myE = eids[min(base + c, hi - 1)];
        int j = 0;
        for (; j + 1 < cnt; j += 2) {
            const int e0 = __shfl(myE, j, 32);
            const int e1 = __shfl(myE, j + 1, 32);
            const f32x4 v0 = __builtin_nontemporal_load(erows + (long long)e0 * D_F4 + c);
            const f32x4 v1 = __builtin_nontemporal_load(erows + (long long)e1 * D_F4 + c);
            a0 += v0;
            a1 += v1;
        }
        if (j < cnt) {
            const int e0 = __shfl(myE, j, 32);
            a0 += __builtin_nontemporal_load(erows + (long long)e0 * D_F4 + c);
        }
    }
    a0 += a1;
    __builtin_nontemporal_store(a0, (f32x4*)out + (long long)g * D_F4 + c);
}

// -------- fallback (atomic version) if ws_size is too small --------
__global__ void seg_sum_atomic(const float4* __restrict__ edges,
                               const int* __restrict__ recv,
                               float* __restrict__ out, int n_edges) {
    const long long total = (long long)n_edges * D_F4;
    long long idx = (long long)blockIdx.x * blockDim.x + threadIdx.x;
    const long long stride = (long long)gridDim.x * blockDim.x;
    for (; idx < total; idx += stride) {
        const int e = (int)(idx >> 5);
        const int c = (int)(idx & 31);
        const float4 v = edges[(long long)e * D_F4 + c];
        const int r = recv[e];
        float* o = out + (long long)r * 128 + c * 4;
        atomicAdd(o + 0, v.x);
        atomicAdd(o + 1, v.y);
        atomicAdd(o + 2, v.z);
        atomicAdd(o + 3, v.w);
    }
}

extern "C" void kernel_launch(void* const* d_in, const int* in_sizes, int n_in,
                              void* d_out, int out_size, void* d_ws, size_t ws_size,
                              hipStream_t stream) {
    const float* edges = (const float*)d_in[0];
    const int* recv = (const int*)d_in[1];
    float* out = (float*)d_out;

    const int E = in_sizes[1];            // 625000
    const int N = out_size / 128;         // 50000 nodes

    // workspace layout (ints), all segments 16B-aligned:
    //   counts[countsPad] | offsets[offsPad] | cursor[N] | eids[E]
    const int countsPad = (N + 3) & ~3;
    const int offsPad = ((N + 1) + 3) & ~3;
    const size_t need = (size_t)(countsPad + offsPad + N + E) * sizeof(int);
    if (ws_size < need) {
        zero_k<<<256, 256, 0, stream>>>((int4*)d_out, out_size / 4);
        const long long total = (long long)E * D_F4;
        int grid = (int)((total + 255) / 256);
        if (grid > 4096) grid = 4096;
        seg_sum_atomic<<<grid, 256, 0, stream>>>((const float4*)edges, recv, out, E);
        return;
    }

    int* counts = (int*)d_ws;
    int* offsets = counts + countsPad;
    int* cursor = offsets + offsPad;
    int* eids = cursor + N;

    const int block = 256;

    zero_k<<<64, block, 0, stream>>>((int4*)counts, countsPad / 4);

    const int E4 = E >> 2;
    const int gridE4 = (E4 + block - 1) / block;   // ~611 blocks, one pass

    hist_k<<<gridE4, block, 0, stream>>>(recv, counts, E);
    scan_k<<<1, 1024, 0, stream>>>(counts, offsets, cursor, N);
    scatter_k<<<gridE4, block, 0, stream>>>(recv, cursor, eids, E);

    const int gridN = (N * 32 + block - 1) / block;  // 32 lanes per node
    gather_k<<<gridN, block, 0, stream>>>(edges, eids, offsets, out, N);
}

// Round 5
// 135.156 us; speedup vs baseline: 7.8395x; 1.2212x over previous
//
#include <hip/hip_runtime.h>
#include <hip/hip_bf16.h>

// segment_sum: out[r] += edges[e] for receivers[e]==r.
// edges: [E=625000, D=128] f32, receivers: [E] i32, out: [N=50000, 128] f32.
//
// R1: f32-atomic scatter: TCC-atomic write-through bound (1.25GB WRITE, 1057us).
// R2: counting-sort + gather (266us). R3: custom zero kernel (249us).
// R4: vectorized aux + eid-shfl broadcast + nt (165us).
// R5 (this):
//   - DROP nt on edge loads: harness poisons once then replays the graph, so
//     320MB of edges can stay ~75% resident in the 256MB Infinity Cache across
//     replays -- nt was forcing full HBM re-fetch. Keep nt on the output store.
//   - gather: 64-lane wave per node PAIR over the pair's concatenated
//     (contiguous!) eid range; 2 rows per load instruction (lane>>5 picks the
//     row), 4-deep unroll = 8 rows in flight/wave; wave-uniform control flow;
//     cross-half merge via __shfl_xor(.,32).
//   - rank-based scatter: hist also records rank[e]; scatter is atomic-free.

#define D_F4 32  // 128 floats = 32 float4 per row

typedef float f32x4 __attribute__((ext_vector_type(4)));

__global__ void zero_k(int4* __restrict__ p, int n_int4) {
    int i = blockIdx.x * blockDim.x + threadIdx.x;
    const int stride = gridDim.x * blockDim.x;
    const int4 z = make_int4(0, 0, 0, 0);
    for (; i < n_int4; i += stride) p[i] = z;
}

// counts[r]++ and remember each edge's arrival rank within its receiver.
__global__ void hist_rank_k(const int* __restrict__ recv, int* __restrict__ counts,
                            int* __restrict__ rank, int E) {
    const int E4 = E >> 2;
    const int i = blockIdx.x * blockDim.x + threadIdx.x;
    const int stride = gridDim.x * blockDim.x;
    for (int k = i; k < E4; k += stride) {
        const int4 r = ((const int4*)recv)[k];
        int4 p;
        p.x = atomicAdd(&counts[r.x], 1);
        p.y = atomicAdd(&counts[r.y], 1);
        p.z = atomicAdd(&counts[r.z], 1);
        p.w = atomicAdd(&counts[r.w], 1);
        ((int4*)rank)[k] = p;
    }
    if (i < (E & 3)) {
        const int e = (E4 << 2) + i;
        rank[e] = atomicAdd(&counts[recv[e]], 1);
    }
}

// One block, 1024 threads: vectorized chunked exclusive scan of counts -> offsets.
__global__ void scan_k(const int* __restrict__ counts, int* __restrict__ offsets, int N) {
    __shared__ int partials[1024];
    const int tid = threadIdx.x;
    int chunk = (N + 1023) >> 10;
    chunk = (chunk + 3) & ~3;
    const int lo = min(tid * chunk, N);
    const int hi = min(lo + chunk, N);

    int s = 0;
    int i = lo;
    for (; i + 4 <= hi; i += 4) {
        const int4 c4 = *(const int4*)(counts + i);
        s += c4.x + c4.y + c4.z + c4.w;
    }
    for (; i < hi; ++i) s += counts[i];
    partials[tid] = s;
    __syncthreads();
    for (int d = 1; d < 1024; d <<= 1) {
        const int v = (tid >= d) ? partials[tid - d] : 0;
        __syncthreads();
        partials[tid] += v;
        __syncthreads();
    }
    int run = (tid > 0) ? partials[tid - 1] : 0;
    i = lo;
    for (; i + 4 <= hi; i += 4) {
        const int4 c4 = *(const int4*)(counts + i);
        int4 o;
        o.x = run;
        o.y = run + c4.x;
        o.z = o.y + c4.y;
        o.w = o.z + c4.z;
        run = o.w + c4.w;
        *(int4*)(offsets + i) = o;
    }
    for (; i < hi; ++i) { offsets[i] = run; run += counts[i]; }
    if (tid == 1023) offsets[N] = partials[1023];
}

// atomic-free: pos = offsets[recv[e]] + rank[e]
__global__ void scatter_k(const int* __restrict__ recv, const int* __restrict__ rank,
                          const int* __restrict__ offsets, int* __restrict__ eids, int E) {
    const int E4 = E >> 2;
    const int i = blockIdx.x * blockDim.x + threadIdx.x;
    const int stride = gridDim.x * blockDim.x;
    for (int k = i; k < E4; k += stride) {
        const int4 r = ((const int4*)recv)[k];
        const int4 p = ((const int4*)rank)[k];
        const int e = k << 2;
        eids[offsets[r.x] + p.x] = e;
        eids[offsets[r.y] + p.y] = e + 1;
        eids[offsets[r.z] + p.z] = e + 2;
        eids[offsets[r.w] + p.w] = e + 3;
    }
    if (i < (E & 3)) {
        const int e = (E4 << 2) + i;
        eids[offsets[recv[e]] + rank[e]] = e;
    }
}

__device__ inline f32x4 xor32(f32x4 v) {
    f32x4 r;
    r.x = __shfl_xor(v.x, 32, 64);
    r.y = __shfl_xor(v.y, 32, 64);
    r.z = __shfl_xor(v.z, 32, 64);
    r.w = __shfl_xor(v.w, 32, 64);
    return r;
}

// One 64-lane wave per node pair (nA, nB). Their eid ranges are adjacent in
// the sorted order, so [offsets[nA], offsets[nB+1]) is one contiguous stream.
// Lanes: c = lane&31 owns float4 column c; h = lane>>5 picks row j or j+1, so
// each load instruction fetches TWO 512B rows. 4-deep unroll = 8 rows in
// flight per wave. Wave-uniform loop bounds (no intra-wave divergence).
__global__ __launch_bounds__(256) void gather_k(const float* __restrict__ edges,
                                                const int* __restrict__ eids,
                                                const int* __restrict__ offsets,
                                                float* __restrict__ out, int N) {
    const int wave = (blockIdx.x * blockDim.x + threadIdx.x) >> 6;
    const int lane = threadIdx.x & 63;
    const int c = lane & 31;
    const int h = lane >> 5;
    const int nA = wave << 1;
    if (nA >= N) return;
    const int nB = nA | 1;
    const int loA = offsets[nA];
    const int loB = offsets[nA + 1];                  // == hiA
    const int hiB = (nB < N) ? offsets[nB + 1] : loB;
    if (loA >= hiB) {
        const f32x4 z = {0.f, 0.f, 0.f, 0.f};
        const int row = h ? nB : nA;
        if (row < N)
            __builtin_nontemporal_store(z, (f32x4*)out + (long long)row * D_F4 + c);
        return;
    }

    const f32x4* __restrict__ erows = (const f32x4*)edges;
    f32x4 a0 = {0,0,0,0}, a1 = {0,0,0,0}, a2 = {0,0,0,0}, a3 = {0,0,0,0};
    f32x4 b0 = {0,0,0,0}, b1 = {0,0,0,0}, b2 = {0,0,0,0}, b3 = {0,0,0,0};

    for (int base = loA; base < hiB; base += 64) {
        const int cnt = min(64, hiB - base);
        const int splitL = min(max(loB - base, 0), cnt);   // local A/B boundary
        const int myE = eids[min(base + lane, hiB - 1)];   // coalesced 64 eids
        int jj = 0;
        // ---- node A rows [0, splitL) ----
        for (; jj + 7 < splitL; jj += 8) {
            const int e0 = __shfl(myE, jj + 0 + h, 64);
            const int e1 = __shfl(myE, jj + 2 + h, 64);
            const int e2 = __shfl(myE, jj + 4 + h, 64);
            const int e3 = __shfl(myE, jj + 6 + h, 64);
            a0 += erows[(long long)e0 * D_F4 + c];
            a1 += erows[(long long)e1 * D_F4 + c];
            a2 += erows[(long long)e2 * D_F4 + c];
            a3 += erows[(long long)e3 * D_F4 + c];
        }
        for (; jj + 1 < splitL; jj += 2) {
            const int e0 = __shfl(myE, jj + h, 64);
            a0 += erows[(long long)e0 * D_F4 + c];
        }
        if (jj < splitL) {  // odd leftover A row: both halves fetch same 512B
            const int e0 = __shfl(myE, jj, 64);
            const f32x4 v = erows[(long long)e0 * D_F4 + c];
            if (h == 0) a1 += v;   // add once
            ++jj;
        }
        // ---- node B rows [splitL, cnt) ----
        for (; jj + 7 < cnt; jj += 8) {
            const int e0 = __shfl(myE, jj + 0 + h, 64);
            const int e1 = __shfl(myE, jj + 2 + h, 64);
            const int e2 = __shfl(myE, jj + 4 + h, 64);
            const int e3 = __shfl(myE, jj + 6 + h, 64);
            b0 += erows[(long long)e0 * D_F4 + c];
            b1 += erows[(long long)e1 * D_F4 + c];
            b2 += erows[(long long)e2 * D_F4 + c];
            b3 += erows[(long long)e3 * D_F4 + c];
        }
        for (; jj + 1 < cnt; jj += 2) {
            const int e0 = __shfl(myE, jj + h, 64);
            b0 += erows[(long long)e0 * D_F4 + c];
        }
        if (jj < cnt) {
            const int e0 = __shfl(myE, jj, 64);
            const f32x4 v = erows[(long long)e0 * D_F4 + c];
            if (h == 0) b1 += v;
        }
    }
    a0 += a1; a2 += a3; a0 += a2;
    b0 += b1; b2 += b3; b0 += b2;
    a0 += xor32(a0);   // both halves now hold full node-A sum
    b0 += xor32(b0);
    const int row = h ? nB : nA;
    const f32x4 r = h ? b0 : a0;
    if (row < N)
        __builtin_nontemporal_store(r, (f32x4*)out + (long long)row * D_F4 + c);
}

// -------- fallback (atomic version) if ws_size is too small --------
__global__ void seg_sum_atomic(const float4* __restrict__ edges,
                               const int* __restrict__ recv,
                               float* __restrict__ out, int n_edges) {
    const long long total = (long long)n_edges * D_F4;
    long long idx = (long long)blockIdx.x * blockDim.x + threadIdx.x;
    const long long stride = (long long)gridDim.x * blockDim.x;
    for (; idx < total; idx += stride) {
        const int e = (int)(idx >> 5);
        const int c = (int)(idx & 31);
        const float4 v = edges[(long long)e * D_F4 + c];
        const int r = recv[e];
        float* o = out + (long long)r * 128 + c * 4;
        atomicAdd(o + 0, v.x);
        atomicAdd(o + 1, v.y);
        atomicAdd(o + 2, v.z);
        atomicAdd(o + 3, v.w);
    }
}

extern "C" void kernel_launch(void* const* d_in, const int* in_sizes, int n_in,
                              void* d_out, int out_size, void* d_ws, size_t ws_size,
                              hipStream_t stream) {
    const float* edges = (const float*)d_in[0];
    const int* recv = (const int*)d_in[1];
    float* out = (float*)d_out;

    const int E = in_sizes[1];            // 625000
    const int N = out_size / 128;         // 50000 nodes

    // workspace (ints), 16B-aligned segments:
    //   counts[countsPad] | offsets[offsPad] | rank[E] | eids[E]
    const int countsPad = (N + 3) & ~3;
    const int offsPad = ((N + 1) + 3) & ~3;
    const size_t need = (size_t)(countsPad + offsPad + 2 * (size_t)E) * sizeof(int);
    if (ws_size < need) {
        zero_k<<<256, 256, 0, stream>>>((int4*)d_out, out_size / 4);
        const long long total = (long long)E * D_F4;
        int grid = (int)((total + 255) / 256);
        if (grid > 4096) grid = 4096;
        seg_sum_atomic<<<grid, 256, 0, stream>>>((const float4*)edges, recv, out, E);
        return;
    }

    int* counts = (int*)d_ws;
    int* offsets = counts + countsPad;
    int* rank = offsets + offsPad;
    int* eids = rank + E;

    const int block = 256;

    zero_k<<<64, block, 0, stream>>>((int4*)counts, countsPad / 4);

    const int E4 = E >> 2;
    const int gridE4 = (E4 + block - 1) / block;

    hist_rank_k<<<gridE4, block, 0, stream>>>(recv, counts, rank, E);
    scan_k<<<1, 1024, 0, stream>>>(counts, offsets, N);
    scatter_k<<<gridE4, block, 0, stream>>>(recv, rank, offsets, eids, E);

    const int nPairs = (N + 1) / 2;                    // one 64-lane wave per pair
    const int gridN = (nPairs * 64 + block - 1) / block;
    gather_k<<<gridN, block, 0, stream>>>(edges, eids, offsets, out, N);
}